// Round 9
// baseline (517.057 us; speedup 1.0000x reference)
//
#include <hip/hip_runtime.h>
#include <hip/hip_bf16.h>

typedef __hip_bfloat16 bf16;
typedef __bf16 bf16x8 __attribute__((ext_vector_type(8)));
typedef _Float16 f16x8 __attribute__((ext_vector_type(8)));
typedef float f32x4 __attribute__((ext_vector_type(4)));

#if __has_builtin(__builtin_amdgcn_rcpf)
#define RCPF(x) __builtin_amdgcn_rcpf(x)
#else
#define RCPF(x) (1.0f / (x))
#endif

// ---------------- sizes ----------------
// B=2, T=2048, D=1024, H=16, HD=64; BT=4096 rows. Inputs f32; output f32.
// Scan: chunked GLA via MFMA. NC=32 chunks of L=64 -> 1024 single-wave blocks.
static constexpr size_t MB = 1ull << 20;
static constexpr size_t KB = 1024;

// ws layout (<= 64 MiB), lifetime-packed:
static constexpr size_t OFF_XXXQ = 0;              // bf16 8MB: xxx, then q
static constexpr size_t OFF_K    = 8 * MB;         // bf16 8MB
static constexpr size_t OFF_V    = 16 * MB;        // bf16 8MB
static constexpr size_t OFF_W    = 24 * MB;        // bf16 8MB  wb = exp(decay)
static constexpr size_t OFF_WQT  = 32 * MB;        // bf16 2MB  [dead after qk gemm]
static constexpr size_t OFF_WKT  = 34 * MB;        // bf16 2MB  [dead after qk gemm]
static constexpr size_t OFF_MP   = 36 * MB;        // f32  4MB  [dead after vg mix]
static constexpr size_t OFF_GATE = 32 * MB;        // bf16 8MB: overwrites wqt/wkt/mp; -> ag in-place
static constexpr size_t OFF_XS0  = 40 * MB;        // bf16 8MB  [dead at scan]
static constexpr size_t OFF_XS1  = 48 * MB;        // bf16 8MB  [dead at scan]
static constexpr size_t OFF_SLOC = 40 * MB;        // f32 [32bh][32c][64v][64k] = 16MB (overlays xs0/xs1)
static constexpr size_t OFF_WVT  = 56 * MB;        // bf16 2MB
static constexpr size_t OFF_WGT  = 58 * MB;        // bf16 2MB
static constexpr size_t OFF_WOT  = 60 * MB;        // bf16 2MB (live till final gemm)
static constexpr size_t OFF_W1T  = 62 * MB;        // bf16 0.5MB [dead after mp gemm]
static constexpr size_t OFF_D    = 62 * MB;        // f32 [32][32][64] = 256KB (overlays dead w1t)
static constexpr size_t OFF_WD1T = 62 * MB + 512 * KB;   // bf16 0.25MB
static constexpr size_t OFF_WD2T = 62 * MB + 768 * KB;   // bf16 0.125MB
static constexpr size_t OFF_DECT = 63 * MB;        // bf16 1MB

// ---------------- helpers ----------------
__device__ __forceinline__ void async_ld16(const void* g, void* l) {
    __builtin_amdgcn_global_load_lds((const __attribute__((address_space(1))) void*)g,
                                     (__attribute__((address_space(3))) void*)l, 16, 0, 0);
}
__device__ __forceinline__ float bf2f(unsigned short u) {
    union { unsigned int i; float f; } x; x.i = ((unsigned int)u) << 16; return x.f;
}
__device__ __forceinline__ unsigned short f2bu(float x) {
    union { bf16 b; unsigned short u; } c; c.b = __float2bfloat16(x); return c.u;
}

// ---------------- fused: 8 weight transposes (f32->bf16, col-pad) + prep_xxx ----------------
__global__ void transpose_all(const float* __restrict__ Wq, const float* __restrict__ Wk,
                              const float* __restrict__ Wv, const float* __restrict__ Wg,
                              const float* __restrict__ Wo, const float* __restrict__ w1,
                              const float* __restrict__ dw1, const float* __restrict__ dw2,
                              bf16* __restrict__ wqt, bf16* __restrict__ wkt,
                              bf16* __restrict__ wvt, bf16* __restrict__ wgt,
                              bf16* __restrict__ wot, bf16* __restrict__ w1t,
                              bf16* __restrict__ wd1t, bf16* __restrict__ wd2t,
                              const float* __restrict__ xg, const float* __restrict__ maax,
                              bf16* __restrict__ xxx) {
    __shared__ bf16 tile[32][33];
    int id = blockIdx.x;
    if (id >= 5568) {   // prep_xxx part: xxx = x + dxprev*maa_x
        int flat = threadIdx.y * 32 + threadIdx.x;
        int i = (id - 5568) * 256 + flat;
        int d = i & 1023;
        int t = (i >> 10) & 2047;
        float xv = xg[i];
        float xp = (t > 0) ? xg[i - 1024] : 0.f;
        xxx[i] = __float2bfloat16(xv + (xp - xv) * maax[d]);
        return;
    }
    const float* src; bf16* dst; int R, C, Cpad, local;
    if      (id < 1024) { src = Wq;  dst = wqt;  R = 1024; C = 1024; Cpad = 1024; local = id; }
    else if (id < 2048) { src = Wk;  dst = wkt;  R = 1024; C = 1024; Cpad = 1024; local = id - 1024; }
    else if (id < 3072) { src = Wv;  dst = wvt;  R = 1024; C = 1024; Cpad = 1024; local = id - 2048; }
    else if (id < 4096) { src = Wg;  dst = wgt;  R = 1024; C = 1024; Cpad = 1024; local = id - 3072; }
    else if (id < 5120) { src = Wo;  dst = wot;  R = 1024; C = 1024; Cpad = 1024; local = id - 4096; }
    else if (id < 5376) { src = w1;  dst = w1t;  R = 1024; C = 160;  Cpad = 256;  local = id - 5120; }
    else if (id < 5504) { src = dw1; dst = wd1t; R = 1024; C = 64;   Cpad = 128;  local = id - 5376; }
    else                { src = dw2; dst = wd2t; R = 64;   C = 1024; Cpad = 1024; local = id - 5504; }
    int Rb = R >> 5;
    int r0 = (local % Rb) * 32, c0 = (local / Rb) * 32;
    int tx = threadIdx.x, ty = threadIdx.y;  // block (32,8)
#pragma unroll
    for (int yy = 0; yy < 4; ++yy) {
        int r = r0 + ty + yy * 8, c = c0 + tx;
        float v = (r < R && c < C) ? src[(size_t)r * C + c] : 0.f;
        tile[ty + yy * 8][tx] = __float2bfloat16(v);
    }
    __syncthreads();
#pragma unroll
    for (int yy = 0; yy < 4; ++yy) {
        int c = c0 + ty + yy * 8, r = r0 + tx;
        if (c < Cpad && r < R) dst[(size_t)c * R + r] = tile[tx][ty + yy * 8];
    }
}

// ---------------- m97-style bf16 MFMA GEMM: C(M,N) = A(M,K) @ Bt(N,K)^T ----------------
// EPI: 1 = f32 tanh; 2 = bf16 tanh; 3 = bf16 w=exp(aux+v); 6 = f32 plain
template<int EPI>
__global__ __launch_bounds__(256)
void gemm_bt(const bf16* __restrict__ A, int lda,
             const bf16* __restrict__ Bt, int ldb,
             void* __restrict__ Cout, int ldc,
             int K, const float* __restrict__ aux)
{
    __shared__ __align__(16) bf16 As[128 * 32];
    __shared__ __align__(16) bf16 Bs[128 * 32];
    const int m0 = blockIdx.x * 128;
    const int n0 = blockIdx.y * 128;
    const int tid = threadIdx.x;
    const int lane = tid & 63;
    const int w = tid >> 6;
    const int wm = w >> 1, wn = w & 1;
    const int row16 = lane & 15;
    const int quad = lane >> 4;

    f32x4 acc[4][4];
#pragma unroll
    for (int mi = 0; mi < 4; ++mi)
#pragma unroll
        for (int ni = 0; ni < 4; ++ni)
            acc[mi][ni] = (f32x4){0.f, 0.f, 0.f, 0.f};

    for (int k0 = 0; k0 < K; k0 += 32) {
        __syncthreads();
#pragma unroll
        for (int j = 0; j < 2; ++j) {
            int i = j * 256 + w * 64 + lane;
            int ri = i >> 2;
            int ci = (i & 3) * 8;
            async_ld16(A  + (size_t)(m0 + ri) * lda + (k0 + ci), As + (size_t)(j * 256 + w * 64) * 8);
            async_ld16(Bt + (size_t)(n0 + ri) * ldb + (k0 + ci), Bs + (size_t)(j * 256 + w * 64) * 8);
        }
        __syncthreads();
        bf16x8 af[4], bfr[4];
#pragma unroll
        for (int mi = 0; mi < 4; ++mi)
            af[mi] = *(const bf16x8*)(As + ((wm * 64 + mi * 16 + row16) * 32 + quad * 8));
#pragma unroll
        for (int ni = 0; ni < 4; ++ni)
            bfr[ni] = *(const bf16x8*)(Bs + ((wn * 64 + ni * 16 + row16) * 32 + quad * 8));
#pragma unroll
        for (int mi = 0; mi < 4; ++mi)
#pragma unroll
            for (int ni = 0; ni < 4; ++ni)
                acc[mi][ni] = __builtin_amdgcn_mfma_f32_16x16x32_bf16(af[mi], bfr[ni], acc[mi][ni], 0, 0, 0);
    }
#pragma unroll
    for (int mi = 0; mi < 4; ++mi)
#pragma unroll
        for (int ni = 0; ni < 4; ++ni)
#pragma unroll
            for (int r = 0; r < 4; ++r) {
                int gr = m0 + wm * 64 + mi * 16 + quad * 4 + r;
                int gc = n0 + wn * 64 + ni * 16 + row16;
                size_t ci = (size_t)gr * ldc + gc;
                float v = acc[mi][ni][r];
                if (EPI == 1) ((float*)Cout)[ci] = tanhf(v);
                else if (EPI == 2) ((bf16*)Cout)[ci] = __float2bfloat16(tanhf(v));
                else if (EPI == 3) {
                    float t = aux[gc] + v;
                    ((bf16*)Cout)[ci] = __float2bfloat16(expf(t));   // w = exp(decay)
                } else {
                    ((float*)Cout)[ci] = v;   // EPI 6
                }
            }
}

// ---------------- batched z=2 GEMM: z selects (A,B,C); z=0 bf16 plain, z=1 EPI1 ----------------
// EPI1: 4 = bf16 silu(v+aux); 5 = bf16 plain
template<int EPI1>
__global__ __launch_bounds__(256)
void gemm_bt2(const bf16* __restrict__ A0, const bf16* __restrict__ A1, int lda,
              const bf16* __restrict__ B0, const bf16* __restrict__ B1, int ldb,
              bf16* __restrict__ C0, bf16* __restrict__ C1, int ldc,
              int K, const float* __restrict__ aux)
{
    __shared__ __align__(16) bf16 As[128 * 32];
    __shared__ __align__(16) bf16 Bs[128 * 32];
    const int z = blockIdx.z;
    const bf16* A  = z ? A1 : A0;
    const bf16* Bt = z ? B1 : B0;
    bf16* Cout     = z ? C1 : C0;
    const int m0 = blockIdx.x * 128;
    const int n0 = blockIdx.y * 128;
    const int tid = threadIdx.x;
    const int lane = tid & 63;
    const int w = tid >> 6;
    const int wm = w >> 1, wn = w & 1;
    const int row16 = lane & 15;
    const int quad = lane >> 4;

    f32x4 acc[4][4];
#pragma unroll
    for (int mi = 0; mi < 4; ++mi)
#pragma unroll
        for (int ni = 0; ni < 4; ++ni)
            acc[mi][ni] = (f32x4){0.f, 0.f, 0.f, 0.f};

    for (int k0 = 0; k0 < K; k0 += 32) {
        __syncthreads();
#pragma unroll
        for (int j = 0; j < 2; ++j) {
            int i = j * 256 + w * 64 + lane;
            int ri = i >> 2;
            int ci = (i & 3) * 8;
            async_ld16(A  + (size_t)(m0 + ri) * lda + (k0 + ci), As + (size_t)(j * 256 + w * 64) * 8);
            async_ld16(Bt + (size_t)(n0 + ri) * ldb + (k0 + ci), Bs + (size_t)(j * 256 + w * 64) * 8);
        }
        __syncthreads();
        bf16x8 af[4], bfr[4];
#pragma unroll
        for (int mi = 0; mi < 4; ++mi)
            af[mi] = *(const bf16x8*)(As + ((wm * 64 + mi * 16 + row16) * 32 + quad * 8));
#pragma unroll
        for (int ni = 0; ni < 4; ++ni)
            bfr[ni] = *(const bf16x8*)(Bs + ((wn * 64 + ni * 16 + row16) * 32 + quad * 8));
#pragma unroll
        for (int mi = 0; mi < 4; ++mi)
#pragma unroll
            for (int ni = 0; ni < 4; ++ni)
                acc[mi][ni] = __builtin_amdgcn_mfma_f32_16x16x32_bf16(af[mi], bfr[ni], acc[mi][ni], 0, 0, 0);
    }
#pragma unroll
    for (int mi = 0; mi < 4; ++mi)
#pragma unroll
        for (int ni = 0; ni < 4; ++ni)
#pragma unroll
            for (int r = 0; r < 4; ++r) {
                int gr = m0 + wm * 64 + mi * 16 + quad * 4 + r;
                int gc = n0 + wn * 64 + ni * 16 + row16;
                size_t ci = (size_t)gr * ldc + gc;
                float v = acc[mi][ni][r];
                if (z == 0 || EPI1 == 5) Cout[ci] = __float2bfloat16(v);
                else {
                    float zz = v + aux[gc];
                    Cout[ci] = __float2bfloat16(zz / (1.f + expf(-zz)));  // silu
                }
            }
}

// ---------------- single stream: xs = x + dxprev * (maa_f + mp_f @ w2_f) ----------------
__global__ __launch_bounds__(256)
void mix_stream(const float* __restrict__ mp, const float* __restrict__ w2,
                const float* __restrict__ x, const float* __restrict__ maa_f,
                int f, bf16* __restrict__ xs)
{
    __shared__ float mps[4][32];
    int dg = blockIdx.x, r0 = blockIdx.y * 4, tid = threadIdx.x;
    int d = dg * 256 + tid;
    if (tid < 128) {
        int rr = tid >> 5, l = tid & 31;
        mps[rr][l] = mp[(size_t)(r0 + rr) * 256 + f * 32 + l];
    }
    __syncthreads();
    float acc[4] = {0.f, 0.f, 0.f, 0.f};
#pragma unroll
    for (int l = 0; l < 32; ++l) {
        float wv = w2[(size_t)(f * 32 + l) * 1024 + d];
#pragma unroll
        for (int rr = 0; rr < 4; ++rr) acc[rr] = fmaf(mps[rr][l], wv, acc[rr]);
    }
    float mf = maa_f[d];
#pragma unroll
    for (int rr = 0; rr < 4; ++rr) {
        int r = r0 + rr, t = r & 2047;
        size_t i = (size_t)r * 1024 + d;
        float xv = x[i];
        float xp = (t > 0) ? x[i - 1024] : 0.f;
        xs[i] = __float2bfloat16(xv + (xp - xv) * (mf + acc[rr]));
    }
}

// ---------------- fused pair of streams sharing x/mp loads ----------------
__global__ __launch_bounds__(256)
void mix_stream2(const float* __restrict__ mp, const float* __restrict__ w2,
                 const float* __restrict__ x,
                 const float* __restrict__ maa_a, const float* __restrict__ maa_b,
                 int fa, int fb, bf16* __restrict__ xsa, bf16* __restrict__ xsb)
{
    __shared__ float mpsa[4][32], mpsb[4][32];
    int dg = blockIdx.x, r0 = blockIdx.y * 4, tid = threadIdx.x;
    int d = dg * 256 + tid;
    if (tid < 128) {
        int rr = tid >> 5, l = tid & 31;
        mpsa[rr][l] = mp[(size_t)(r0 + rr) * 256 + fa * 32 + l];
        mpsb[rr][l] = mp[(size_t)(r0 + rr) * 256 + fb * 32 + l];
    }
    __syncthreads();
    float acca[4] = {0.f, 0.f, 0.f, 0.f}, accb[4] = {0.f, 0.f, 0.f, 0.f};
#pragma unroll
    for (int l = 0; l < 32; ++l) {
        float wa = w2[(size_t)(fa * 32 + l) * 1024 + d];
        float wbv = w2[(size_t)(fb * 32 + l) * 1024 + d];
#pragma unroll
        for (int rr = 0; rr < 4; ++rr) {
            acca[rr] = fmaf(mpsa[rr][l], wa, acca[rr]);
            accb[rr] = fmaf(mpsb[rr][l], wbv, accb[rr]);
        }
    }
    float ma = maa_a[d], mb = maa_b[d];
#pragma unroll
    for (int rr = 0; rr < 4; ++rr) {
        int r = r0 + rr, t = r & 2047;
        size_t i = (size_t)r * 1024 + d;
        float xv = x[i];
        float xp = (t > 0) ? x[i - 1024] : 0.f;
        float dx = xp - xv;
        xsa[i] = __float2bfloat16(xv + dx * (ma + acca[rr]));
        xsb[i] = __float2bfloat16(xv + dx * (mb + accb[rr]));
    }
}

// ================= chunked GLA scan via MFMA: NC=32, L=64, single-wave blocks =================
// LDS matrices use element stride 72 (rows 144B, 16B-aligned; ~2-way bank aliasing = free).

// Phase A: Sloc[v][k] = (Vt @ KiA) * aL[k], D[k] = aL[k].  KiA[t][k] = kb*exp(cum).
__global__ __launch_bounds__(64)
void chunk_state(const bf16* __restrict__ kG, const bf16* __restrict__ vG,
                 const bf16* __restrict__ wG,
                 float* __restrict__ Sloc, float* __restrict__ D)
{
    int c = blockIdx.x, bh = blockIdx.y;
    int b = bh >> 4, h = bh & 15;
    int lane = threadIdx.x;
    int row16 = lane & 15, quad = lane >> 4;
    __shared__ __align__(16) char smem[2 * 9216 + 256];
    bf16* sKiAt = (bf16*)smem;             // [k][t]
    bf16* sVt   = (bf16*)(smem + 9216);    // [v][t]
    float* aLs  = (float*)(smem + 18432);
    size_t base = (size_t)b * 2048 * 1024 + (size_t)h * 64 + (size_t)c * 64 * 1024;

    const unsigned short* kp = (const unsigned short*)kG;
    const unsigned short* vp = (const unsigned short*)vG;
    const unsigned short* wp = (const unsigned short*)wG;
    unsigned short kr[4], vr[4], wr[4];
#pragma unroll
    for (int j = 0; j < 4; ++j) {
        size_t a = base + (size_t)j * 1024 + lane;
        kr[j] = kp[a]; vr[j] = vp[a]; wr[j] = wp[a];
    }
    float A = 1.f;
    union { unsigned short u[8]; uint4 q; } pk, pv;
    for (int t = 0; t < 64; ++t) {
        int slot = t & 3;
        float kl = bf2f(kr[slot]);
        float vl = bf2f(vr[slot]);
        float wl = bf2f(wr[slot]);
        if (t + 4 < 64) {
            size_t a = base + (size_t)(t + 4) * 1024 + lane;
            kr[slot] = kp[a]; vr[slot] = vp[a]; wr[slot] = wp[a];
        }
        float el = __expf(-wl);
        A *= el;
        float kb = kl * (1.f - el);
        float invA = RCPF(A);
        pk.u[t & 7] = f2bu(kb * invA);
        pv.u[t & 7] = f2bu(vl);
        if ((t & 7) == 7) {
            *(uint4*)(sKiAt + lane * 72 + (t - 7)) = pk.q;
            *(uint4*)(sVt   + lane * 72 + (t - 7)) = pv.q;
        }
    }
    aLs[lane] = A;
    D[((size_t)bh * 32 + c) * 64 + lane] = A;
    __syncthreads();

    f32x4 acc[4][4];
#pragma unroll
    for (int mi = 0; mi < 4; ++mi)
#pragma unroll
        for (int ni = 0; ni < 4; ++ni) acc[mi][ni] = (f32x4){0.f, 0.f, 0.f, 0.f};
#pragma unroll
    for (int kit = 0; kit < 2; ++kit) {
        bf16x8 af[4], bfr[4];
#pragma unroll
        for (int mi = 0; mi < 4; ++mi)
            af[mi] = *(const bf16x8*)(sVt + (mi * 16 + row16) * 72 + kit * 32 + quad * 8);
#pragma unroll
        for (int ni = 0; ni < 4; ++ni)
            bfr[ni] = *(const bf16x8*)(sKiAt + (ni * 16 + row16) * 72 + kit * 32 + quad * 8);
#pragma unroll
        for (int mi = 0; mi < 4; ++mi)
#pragma unroll
            for (int ni = 0; ni < 4; ++ni)
                acc[mi][ni] = __builtin_amdgcn_mfma_f32_16x16x32_bf16(af[mi], bfr[ni], acc[mi][ni], 0, 0, 0);
    }
    float* So = Sloc + ((size_t)bh * 32 + c) * 4096;
#pragma unroll
    for (int mi = 0; mi < 4; ++mi)
#pragma unroll
        for (int ni = 0; ni < 4; ++ni)
#pragma unroll
            for (int r = 0; r < 4; ++r) {
                int rv = mi * 16 + quad * 4 + r;   // v
                int ck = ni * 16 + row16;          // k
                So[(size_t)rv * 64 + ck] = acc[mi][ni][r] * aLs[ck];
            }
}

// Phase B: S0_{c+1} = S0_c*D_c + Sloc_c (exact f32); Sloc_c := S0_c.
__global__ __launch_bounds__(256)
void chunk_combine(float* __restrict__ Sloc, const float* __restrict__ D)
{
    int bh = blockIdx.x;
    int tid = threadIdx.x;
    int k = tid & 63, v0 = tid >> 6;
    float s[16];
#pragma unroll
    for (int j = 0; j < 16; ++j) s[j] = 0.f;
    for (int c = 0; c < 32; ++c) {
        float Dk = D[((size_t)bh * 32 + c) * 64 + k];
        size_t basei = ((size_t)bh * 32 + c) * 4096 + k;
#pragma unroll
        for (int j = 0; j < 16; ++j) {
            size_t idx = basei + (size_t)(v0 + j * 4) * 64;
            float tmp = Sloc[idx];
            Sloc[idx] = s[j];
            s[j] = s[j] * Dk + tmp;
        }
    }
}

// Phase C: P=(Q⊙A)(KB⊘A)^T masked; O = P@V + (Q⊙A)@S0; ag = O*gate (in-place).
__global__ __launch_bounds__(64)
void chunk_out(const bf16* __restrict__ qG, const bf16* __restrict__ kG,
               const bf16* __restrict__ vG, const bf16* __restrict__ wG,
               const bf16* gate, const float* __restrict__ S0buf, bf16* ag)
{
    int c = blockIdx.x, bh = blockIdx.y;
    int b = bh >> 4, h = bh & 15;
    int lane = threadIdx.x;
    int row16 = lane & 15, quad = lane >> 4;
    __shared__ __align__(16) char smem[4 * 9216];
    bf16*     sQA = (bf16*)smem;                  // [t][k] bf16
    bf16*     sKiA = (bf16*)(smem + 9216);        // [s][k] bf16; later P
    _Float16* sP  = (_Float16*)(smem + 9216);     // [t][s] f16 (overlays sKiA)
    _Float16* sVt = (_Float16*)(smem + 18432);    // [v][s] f16
    bf16*     sS0 = (bf16*)(smem + 27648);        // [v][k] bf16
    float*    Obuf = (float*)smem;                // [t][v] f32 (overlays sQA+sP after MFMA)
    size_t base = (size_t)b * 2048 * 1024 + (size_t)h * 64 + (size_t)c * 64 * 1024;

    // stage S0 (chunk-start state; buffer[v][k] = math S0[k][v] = Bt-form for QA@S0)
    const float* S0g = S0buf + ((size_t)bh * 32 + c) * 4096;
#pragma unroll 8
    for (int i = 0; i < 64; ++i)
        sS0[i * 72 + lane] = __float2bfloat16(S0g[(size_t)i * 64 + lane]);

    // prep: lane = k (and v for Vt)
    const unsigned short* qp = (const unsigned short*)qG;
    const unsigned short* kp = (const unsigned short*)kG;
    const unsigned short* vp = (const unsigned short*)vG;
    const unsigned short* wp = (const unsigned short*)wG;
    unsigned short qr[4], kr[4], vr[4], wr[4];
#pragma unroll
    for (int j = 0; j < 4; ++j) {
        size_t a = base + (size_t)j * 1024 + lane;
        qr[j] = qp[a]; kr[j] = kp[a]; vr[j] = vp[a]; wr[j] = wp[a];
    }
    float A = 1.f;
    union { _Float16 hp[8]; uint4 q; } pv;
    for (int t = 0; t < 64; ++t) {
        int slot = t & 3;
        float ql = bf2f(qr[slot]);
        float kl = bf2f(kr[slot]);
        float vl = bf2f(vr[slot]);
        float wl = bf2f(wr[slot]);
        if (t + 4 < 64) {
            size_t a = base + (size_t)(t + 4) * 1024 + lane;
            qr[slot] = qp[a]; kr[slot] = kp[a]; vr[slot] = vp[a]; wr[slot] = wp[a];
        }
        float el = __expf(-wl);
        A *= el;
        float kb = kl * (1.f - el);
        float invA = RCPF(A);
        sQA[t * 72 + lane]  = __float2bfloat16(ql * 0.125f * A);
        sKiA[t * 72 + lane] = __float2bfloat16(kb * invA);
        pv.hp[t & 7] = (_Float16)vl;
        if ((t & 7) == 7) *(uint4*)(sVt + lane * 72 + (t - 7)) = pv.q;
    }
    __syncthreads();

    // P = QA @ KiA^T  (contraction over k)
    f32x4 pacc[4][4];
#pragma unroll
    for (int mi = 0; mi < 4; ++mi)
#pragma unroll
        for (int ni = 0; ni < 4; ++ni) pacc[mi][ni] = (f32x4){0.f, 0.f, 0.f, 0.f};
#pragma unroll
    for (int kit = 0; kit < 2; ++kit) {
        bf16x8 af[4], bfr[4];
#pragma unroll
        for (int mi = 0; mi < 4; ++mi)
            af[mi] = *(const bf16x8*)(sQA + (mi * 16 + row16) * 72 + kit * 32 + quad * 8);
#pragma unroll
        for (int ni = 0; ni < 4; ++ni)
            bfr[ni] = *(const bf16x8*)(sKiA + (ni * 16 + row16) * 72 + kit * 32 + quad * 8);
#pragma unroll
        for (int mi = 0; mi < 4; ++mi)
#pragma unroll
            for (int ni = 0; ni < 4; ++ni)
                pacc[mi][ni] = __builtin_amdgcn_mfma_f32_16x16x32_bf16(af[mi], bfr[ni], pacc[mi][ni], 0, 0, 0);
    }
    __syncthreads();
    // mask (s<=t) and store P as f16 over sKiA
#pragma unroll
    for (int mi = 0; mi < 4; ++mi)
#pragma unroll
        for (int ni = 0; ni < 4; ++ni)
#pragma unroll
            for (int r = 0; r < 4; ++r) {
                int rowt = mi * 16 + quad * 4 + r;
                int cols = ni * 16 + row16;
                float pvv = (cols <= rowt) ? pacc[mi][ni][r] : 0.f;
                sP[rowt * 72 + cols] = (_Float16)pvv;
            }
    __syncthreads();

    // O = P @ V (f16) + QA @ S0 (bf16)
    f32x4 oacc[4][4];
#pragma unroll
    for (int mi = 0; mi < 4; ++mi)
#pragma unroll
        for (int ni = 0; ni < 4; ++ni) oacc[mi][ni] = (f32x4){0.f, 0.f, 0.f, 0.f};
#pragma unroll
    for (int kit = 0; kit < 2; ++kit) {
        f16x8 af[4], bfr[4];
#pragma unroll
        for (int mi = 0; mi < 4; ++mi)
            af[mi] = *(const f16x8*)(sP + (mi * 16 + row16) * 72 + kit * 32 + quad * 8);
#pragma unroll
        for (int ni = 0; ni < 4; ++ni)
            bfr[ni] = *(const f16x8*)(sVt + (ni * 16 + row16) * 72 + kit * 32 + quad * 8);
#pragma unroll
        for (int mi = 0; mi < 4; ++mi)
#pragma unroll
            for (int ni = 0; ni < 4; ++ni)
                oacc[mi][ni] = __builtin_amdgcn_mfma_f32_16x16x32_f16(af[mi], bfr[ni], oacc[mi][ni], 0, 0, 0);
    }
#pragma unroll
    for (int kit = 0; kit < 2; ++kit) {
        bf16x8 af[4], bfr[4];
#pragma unroll
        for (int mi = 0; mi < 4; ++mi)
            af[mi] = *(const bf16x8*)(sQA + (mi * 16 + row16) * 72 + kit * 32 + quad * 8);
#pragma unroll
        for (int ni = 0; ni < 4; ++ni)
            bfr[ni] = *(const bf16x8*)(sS0 + (ni * 16 + row16) * 72 + kit * 32 + quad * 8);
#pragma unroll
        for (int mi = 0; mi < 4; ++mi)
#pragma unroll
            for (int ni = 0; ni < 4; ++ni)
                oacc[mi][ni] = __builtin_amdgcn_mfma_f32_16x16x32_bf16(af[mi], bfr[ni], oacc[mi][ni], 0, 0, 0);
    }
    __syncthreads();
    // O -> LDS (f32, overlays sQA/sP — all MFMA reads complete)
#pragma unroll
    for (int mi = 0; mi < 4; ++mi)
#pragma unroll
        for (int ni = 0; ni < 4; ++ni)
#pragma unroll
            for (int r = 0; r < 4; ++r)
                Obuf[(mi * 16 + quad * 4 + r) * 72 + ni * 16 + row16] = oacc[mi][ni][r];
    __syncthreads();
    // epilogue: coalesced gate-multiply, in-place into ag(=gate buffer)
    const unsigned short* gp = (const unsigned short*)gate;
#pragma unroll 8
    for (int t = 0; t < 64; ++t) {
        size_t ad = base + (size_t)t * 1024 + lane;
        float o = Obuf[t * 72 + lane];
        float g = bf2f(gp[ad]);
        ag[ad] = __float2bfloat16(o * g);
    }
}

// ---------------- launch ----------------
extern "C" void kernel_launch(void* const* d_in, const int* in_sizes, int n_in,
                              void* d_out, int out_size, void* d_ws, size_t ws_size,
                              hipStream_t stream) {
    const float* x    = (const float*)d_in[0];
    const float* maax = (const float*)d_in[1];
    const float* maar = (const float*)d_in[2];
    const float* maak = (const float*)d_in[3];
    const float* maav = (const float*)d_in[4];
    const float* maaw = (const float*)d_in[5];
    const float* maag = (const float*)d_in[6];
    const float* w1   = (const float*)d_in[7];
    const float* w2   = (const float*)d_in[8];
    const float* td   = (const float*)d_in[9];
    const float* dw1  = (const float*)d_in[10];
    const float* dw2  = (const float*)d_in[11];
    const float* Wq   = (const float*)d_in[12];
    const float* Wk   = (const float*)d_in[13];
    const float* Wv   = (const float*)d_in[14];
    const float* Wo   = (const float*)d_in[15];
    const float* Wg   = (const float*)d_in[16];
    const float* bg   = (const float*)d_in[17];

    char* ws = (char*)d_ws;
    bf16*  xxx   = (bf16*) (ws + OFF_XXXQ);
    bf16*  qb    = (bf16*) (ws + OFF_XXXQ);
    bf16*  kb    = (bf16*) (ws + OFF_K);
    bf16*  vb    = (bf16*) (ws + OFF_V);
    bf16*  wb    = (bf16*) (ws + OFF_W);
    bf16*  gateb = (bf16*) (ws + OFF_GATE);
    bf16*  wqt   = (bf16*) (ws + OFF_WQT);
    bf16*  wkt   = (bf16*) (ws + OFF_WKT);
    float* mp    = (float*)(ws + OFF_MP);
    bf16*  xs0   = (bf16*) (ws + OFF_XS0);
    bf16*  xs1   = (bf16*) (ws + OFF_XS1);
    bf16*  wvt   = (bf16*) (ws + OFF_WVT);
    bf16*  wgt   = (bf16*) (ws + OFF_WGT);
    bf16*  wot   = (bf16*) (ws + OFF_WOT);
    bf16*  w1t   = (bf16*) (ws + OFF_W1T);
    bf16*  wd1t  = (bf16*) (ws + OFF_WD1T);
    bf16*  wd2t  = (bf16*) (ws + OFF_WD2T);
    bf16*  dect  = (bf16*) (ws + OFF_DECT);
    float* Sloc  = (float*)(ws + OFF_SLOC);   // overlays dead xs0/xs1
    float* Dbuf  = (float*)(ws + OFF_D);      // overlays dead w1t

    // fused transposes + prep_xxx
    transpose_all<<<5568 + 16384, dim3(32, 8), 0, stream>>>(
        Wq, Wk, Wv, Wg, Wo, w1, dw1, dw2,
        wqt, wkt, wvt, wgt, wot, w1t, wd1t, wd2t, x, maax, xxx);

    // mp = tanh(xxx @ W1)
    gemm_bt<1><<<dim3(32, 2), 256, 0, stream>>>(xxx, 1024, w1t, 1024, mp, 256, 1024, nullptr);

    // decay chain: xw -> dect -> wb = exp(decay)
    mix_stream<<<dim3(4, 1024), 256, 0, stream>>>(mp, w2, x, maaw, 3, xs0);
    gemm_bt<2><<<dim3(32, 1), 256, 0, stream>>>(xs0, 1024, wd1t, 1024, dect, 128, 1024, nullptr);
    gemm_bt<3><<<dim3(32, 8), 256, 0, stream>>>(dect, 128, wd2t, 64, wb, 1024, 64, td);

    // streams r,k -> q,k (batched)
    mix_stream2<<<dim3(4, 1024), 256, 0, stream>>>(mp, w2, x, maar, maak, 0, 1, xs0, xs1);
    gemm_bt2<5><<<dim3(32, 8, 2), 256, 0, stream>>>(xs0, xs1, 1024, wqt, wkt, 1024,
                                                    qb, kb, 1024, 1024, nullptr);

    // streams v,g -> v,gate (batched; gate overwrites dead wqt/wkt/mp)
    mix_stream2<<<dim3(4, 1024), 256, 0, stream>>>(mp, w2, x, maav, maag, 2, 4, xs0, xs1);
    gemm_bt2<4><<<dim3(32, 8, 2), 256, 0, stream>>>(xs0, xs1, 1024, wvt, wgt, 1024,
                                                    vb, gateb, 1024, 1024, bg);

    // chunked GLA scan via MFMA: NC=32, L=64
    chunk_state  <<<dim3(32, 32),  64, 0, stream>>>(kb, vb, wb, Sloc, Dbuf);
    chunk_combine<<<32,           256, 0, stream>>>(Sloc, Dbuf);
    chunk_out    <<<dim3(32, 32),  64, 0, stream>>>(qb, kb, vb, wb, gateb, Sloc, gateb);

    // out = (o*gate) @ Wo -> f32
    gemm_bt<6><<<dim3(32, 8), 256, 0, stream>>>(gateb, 1024, wot, 1024, (float*)d_out, 1024, 1024, nullptr);

    (void)in_sizes; (void)n_in; (void)out_size; (void)ws_size;
}

// Round 10
// 455.716 us; speedup vs baseline: 1.1346x; 1.1346x over previous
//
#include <hip/hip_runtime.h>
#include <hip/hip_bf16.h>

typedef __hip_bfloat16 bf16;
typedef __bf16 bf16x8 __attribute__((ext_vector_type(8)));
typedef _Float16 f16x8 __attribute__((ext_vector_type(8)));
typedef float f32x4 __attribute__((ext_vector_type(4)));

#if __has_builtin(__builtin_amdgcn_rcpf)
#define RCPF(x) __builtin_amdgcn_rcpf(x)
#else
#define RCPF(x) (1.0f / (x))
#endif

// ---------------- sizes ----------------
// B=2, T=2048, D=1024, H=16, HD=64; BT=4096 rows. Inputs f32; output f32.
// Scan: chunked GLA via MFMA. NC=32 chunks of L=64 -> 1024 single-wave blocks.
static constexpr size_t MB = 1ull << 20;
static constexpr size_t KB = 1024;

// ws layout (<= 64 MiB), lifetime-packed:
static constexpr size_t OFF_XXXQ = 0;              // bf16 8MB: xxx, then q
static constexpr size_t OFF_K    = 8 * MB;         // bf16 8MB
static constexpr size_t OFF_V    = 16 * MB;        // bf16 8MB
static constexpr size_t OFF_W    = 24 * MB;        // bf16 8MB  wb = exp(decay)
static constexpr size_t OFF_WQT  = 32 * MB;        // bf16 2MB  [dead after qk gemm]
static constexpr size_t OFF_WKT  = 34 * MB;        // bf16 2MB  [dead after qk gemm]
static constexpr size_t OFF_MP   = 36 * MB;        // f32  4MB  [dead after vg mix]
static constexpr size_t OFF_GATE = 32 * MB;        // bf16 8MB: overwrites wqt/wkt/mp; -> ag in-place
static constexpr size_t OFF_XS0  = 40 * MB;        // bf16 8MB  [dead at scan]
static constexpr size_t OFF_XS1  = 48 * MB;        // bf16 8MB  [dead at scan]
static constexpr size_t OFF_SLOC = 40 * MB;        // f32 [32bh][32c][64v][64k] = 16MB (overlays xs0/xs1)
static constexpr size_t OFF_WVT  = 56 * MB;        // bf16 2MB
static constexpr size_t OFF_WGT  = 58 * MB;        // bf16 2MB
static constexpr size_t OFF_WOT  = 60 * MB;        // bf16 2MB (live till final gemm)
static constexpr size_t OFF_W1T  = 62 * MB;        // bf16 0.5MB [dead after mp gemm]
static constexpr size_t OFF_D    = 62 * MB;        // f32 [32][32][64] = 256KB (overlays dead w1t)
static constexpr size_t OFF_WD1T = 62 * MB + 512 * KB;   // bf16 0.25MB
static constexpr size_t OFF_WD2T = 62 * MB + 768 * KB;   // bf16 0.125MB
static constexpr size_t OFF_DECT = 63 * MB;        // bf16 1MB

// ---------------- helpers ----------------
__device__ __forceinline__ void async_ld16(const void* g, void* l) {
    __builtin_amdgcn_global_load_lds((const __attribute__((address_space(1))) void*)g,
                                     (__attribute__((address_space(3))) void*)l, 16, 0, 0);
}
__device__ __forceinline__ float bf2f(unsigned short u) {
    union { unsigned int i; float f; } x; x.i = ((unsigned int)u) << 16; return x.f;
}
__device__ __forceinline__ unsigned short f2bu(float x) {
    union { bf16 b; unsigned short u; } c; c.b = __float2bfloat16(x); return c.u;
}

// ---------------- fused: 8 weight transposes (f32->bf16, col-pad) + prep_xxx ----------------
__global__ void transpose_all(const float* __restrict__ Wq, const float* __restrict__ Wk,
                              const float* __restrict__ Wv, const float* __restrict__ Wg,
                              const float* __restrict__ Wo, const float* __restrict__ w1,
                              const float* __restrict__ dw1, const float* __restrict__ dw2,
                              bf16* __restrict__ wqt, bf16* __restrict__ wkt,
                              bf16* __restrict__ wvt, bf16* __restrict__ wgt,
                              bf16* __restrict__ wot, bf16* __restrict__ w1t,
                              bf16* __restrict__ wd1t, bf16* __restrict__ wd2t,
                              const float* __restrict__ xg, const float* __restrict__ maax,
                              bf16* __restrict__ xxx) {
    __shared__ bf16 tile[32][33];
    int id = blockIdx.x;
    if (id >= 5568) {   // prep_xxx part: xxx = x + dxprev*maa_x
        int flat = threadIdx.y * 32 + threadIdx.x;
        int i = (id - 5568) * 256 + flat;
        int d = i & 1023;
        int t = (i >> 10) & 2047;
        float xv = xg[i];
        float xp = (t > 0) ? xg[i - 1024] : 0.f;
        xxx[i] = __float2bfloat16(xv + (xp - xv) * maax[d]);
        return;
    }
    const float* src; bf16* dst; int R, C, Cpad, local;
    if      (id < 1024) { src = Wq;  dst = wqt;  R = 1024; C = 1024; Cpad = 1024; local = id; }
    else if (id < 2048) { src = Wk;  dst = wkt;  R = 1024; C = 1024; Cpad = 1024; local = id - 1024; }
    else if (id < 3072) { src = Wv;  dst = wvt;  R = 1024; C = 1024; Cpad = 1024; local = id - 2048; }
    else if (id < 4096) { src = Wg;  dst = wgt;  R = 1024; C = 1024; Cpad = 1024; local = id - 3072; }
    else if (id < 5120) { src = Wo;  dst = wot;  R = 1024; C = 1024; Cpad = 1024; local = id - 4096; }
    else if (id < 5376) { src = w1;  dst = w1t;  R = 1024; C = 160;  Cpad = 256;  local = id - 5120; }
    else if (id < 5504) { src = dw1; dst = wd1t; R = 1024; C = 64;   Cpad = 128;  local = id - 5376; }
    else                { src = dw2; dst = wd2t; R = 64;   C = 1024; Cpad = 1024; local = id - 5504; }
    int Rb = R >> 5;
    int r0 = (local % Rb) * 32, c0 = (local / Rb) * 32;
    int tx = threadIdx.x, ty = threadIdx.y;  // block (32,8)
#pragma unroll
    for (int yy = 0; yy < 4; ++yy) {
        int r = r0 + ty + yy * 8, c = c0 + tx;
        float v = (r < R && c < C) ? src[(size_t)r * C + c] : 0.f;
        tile[ty + yy * 8][tx] = __float2bfloat16(v);
    }
    __syncthreads();
#pragma unroll
    for (int yy = 0; yy < 4; ++yy) {
        int c = c0 + ty + yy * 8, r = r0 + tx;
        if (c < Cpad && r < R) dst[(size_t)c * R + r] = tile[tx][ty + yy * 8];
    }
}

// ---------------- m97-style bf16 MFMA GEMM: C(M,N) = A(M,K) @ Bt(N,K)^T ----------------
// EPI: 1 = f32 tanh; 2 = bf16 tanh; 3 = bf16 w=exp(aux+v); 6 = f32 plain
template<int EPI>
__global__ __launch_bounds__(256)
void gemm_bt(const bf16* __restrict__ A, int lda,
             const bf16* __restrict__ Bt, int ldb,
             void* __restrict__ Cout, int ldc,
             int K, const float* __restrict__ aux)
{
    __shared__ __align__(16) bf16 As[128 * 32];
    __shared__ __align__(16) bf16 Bs[128 * 32];
    const int m0 = blockIdx.x * 128;
    const int n0 = blockIdx.y * 128;
    const int tid = threadIdx.x;
    const int lane = tid & 63;
    const int w = tid >> 6;
    const int wm = w >> 1, wn = w & 1;
    const int row16 = lane & 15;
    const int quad = lane >> 4;

    f32x4 acc[4][4];
#pragma unroll
    for (int mi = 0; mi < 4; ++mi)
#pragma unroll
        for (int ni = 0; ni < 4; ++ni)
            acc[mi][ni] = (f32x4){0.f, 0.f, 0.f, 0.f};

    for (int k0 = 0; k0 < K; k0 += 32) {
        __syncthreads();
#pragma unroll
        for (int j = 0; j < 2; ++j) {
            int i = j * 256 + w * 64 + lane;
            int ri = i >> 2;
            int ci = (i & 3) * 8;
            async_ld16(A  + (size_t)(m0 + ri) * lda + (k0 + ci), As + (size_t)(j * 256 + w * 64) * 8);
            async_ld16(Bt + (size_t)(n0 + ri) * ldb + (k0 + ci), Bs + (size_t)(j * 256 + w * 64) * 8);
        }
        __syncthreads();
        bf16x8 af[4], bfr[4];
#pragma unroll
        for (int mi = 0; mi < 4; ++mi)
            af[mi] = *(const bf16x8*)(As + ((wm * 64 + mi * 16 + row16) * 32 + quad * 8));
#pragma unroll
        for (int ni = 0; ni < 4; ++ni)
            bfr[ni] = *(const bf16x8*)(Bs + ((wn * 64 + ni * 16 + row16) * 32 + quad * 8));
#pragma unroll
        for (int mi = 0; mi < 4; ++mi)
#pragma unroll
            for (int ni = 0; ni < 4; ++ni)
                acc[mi][ni] = __builtin_amdgcn_mfma_f32_16x16x32_bf16(af[mi], bfr[ni], acc[mi][ni], 0, 0, 0);
    }
#pragma unroll
    for (int mi = 0; mi < 4; ++mi)
#pragma unroll
        for (int ni = 0; ni < 4; ++ni)
#pragma unroll
            for (int r = 0; r < 4; ++r) {
                int gr = m0 + wm * 64 + mi * 16 + quad * 4 + r;
                int gc = n0 + wn * 64 + ni * 16 + row16;
                size_t ci = (size_t)gr * ldc + gc;
                float v = acc[mi][ni][r];
                if (EPI == 1) ((float*)Cout)[ci] = tanhf(v);
                else if (EPI == 2) ((bf16*)Cout)[ci] = __float2bfloat16(tanhf(v));
                else if (EPI == 3) {
                    float t = aux[gc] + v;
                    ((bf16*)Cout)[ci] = __float2bfloat16(expf(t));   // w = exp(decay)
                } else {
                    ((float*)Cout)[ci] = v;   // EPI 6
                }
            }
}

// ---------------- batched z=2 GEMM: z selects (A,B,C); z=0 bf16 plain, z=1 EPI1 ----------------
// EPI1: 4 = bf16 silu(v+aux); 5 = bf16 plain
template<int EPI1>
__global__ __launch_bounds__(256)
void gemm_bt2(const bf16* __restrict__ A0, const bf16* __restrict__ A1, int lda,
              const bf16* __restrict__ B0, const bf16* __restrict__ B1, int ldb,
              bf16* __restrict__ C0, bf16* __restrict__ C1, int ldc,
              int K, const float* __restrict__ aux)
{
    __shared__ __align__(16) bf16 As[128 * 32];
    __shared__ __align__(16) bf16 Bs[128 * 32];
    const int z = blockIdx.z;
    const bf16* A  = z ? A1 : A0;
    const bf16* Bt = z ? B1 : B0;
    bf16* Cout     = z ? C1 : C0;
    const int m0 = blockIdx.x * 128;
    const int n0 = blockIdx.y * 128;
    const int tid = threadIdx.x;
    const int lane = tid & 63;
    const int w = tid >> 6;
    const int wm = w >> 1, wn = w & 1;
    const int row16 = lane & 15;
    const int quad = lane >> 4;

    f32x4 acc[4][4];
#pragma unroll
    for (int mi = 0; mi < 4; ++mi)
#pragma unroll
        for (int ni = 0; ni < 4; ++ni)
            acc[mi][ni] = (f32x4){0.f, 0.f, 0.f, 0.f};

    for (int k0 = 0; k0 < K; k0 += 32) {
        __syncthreads();
#pragma unroll
        for (int j = 0; j < 2; ++j) {
            int i = j * 256 + w * 64 + lane;
            int ri = i >> 2;
            int ci = (i & 3) * 8;
            async_ld16(A  + (size_t)(m0 + ri) * lda + (k0 + ci), As + (size_t)(j * 256 + w * 64) * 8);
            async_ld16(Bt + (size_t)(n0 + ri) * ldb + (k0 + ci), Bs + (size_t)(j * 256 + w * 64) * 8);
        }
        __syncthreads();
        bf16x8 af[4], bfr[4];
#pragma unroll
        for (int mi = 0; mi < 4; ++mi)
            af[mi] = *(const bf16x8*)(As + ((wm * 64 + mi * 16 + row16) * 32 + quad * 8));
#pragma unroll
        for (int ni = 0; ni < 4; ++ni)
            bfr[ni] = *(const bf16x8*)(Bs + ((wn * 64 + ni * 16 + row16) * 32 + quad * 8));
#pragma unroll
        for (int mi = 0; mi < 4; ++mi)
#pragma unroll
            for (int ni = 0; ni < 4; ++ni)
                acc[mi][ni] = __builtin_amdgcn_mfma_f32_16x16x32_bf16(af[mi], bfr[ni], acc[mi][ni], 0, 0, 0);
    }
#pragma unroll
    for (int mi = 0; mi < 4; ++mi)
#pragma unroll
        for (int ni = 0; ni < 4; ++ni)
#pragma unroll
            for (int r = 0; r < 4; ++r) {
                int gr = m0 + wm * 64 + mi * 16 + quad * 4 + r;
                int gc = n0 + wn * 64 + ni * 16 + row16;
                size_t ci = (size_t)gr * ldc + gc;
                float v = acc[mi][ni][r];
                if (z == 0 || EPI1 == 5) Cout[ci] = __float2bfloat16(v);
                else {
                    float zz = v + aux[gc];
                    Cout[ci] = __float2bfloat16(zz / (1.f + expf(-zz)));  // silu
                }
            }
}

// ---------------- single stream: xs = x + dxprev * (maa_f + mp_f @ w2_f) ----------------
__global__ __launch_bounds__(256)
void mix_stream(const float* __restrict__ mp, const float* __restrict__ w2,
                const float* __restrict__ x, const float* __restrict__ maa_f,
                int f, bf16* __restrict__ xs)
{
    __shared__ float mps[4][32];
    int dg = blockIdx.x, r0 = blockIdx.y * 4, tid = threadIdx.x;
    int d = dg * 256 + tid;
    if (tid < 128) {
        int rr = tid >> 5, l = tid & 31;
        mps[rr][l] = mp[(size_t)(r0 + rr) * 256 + f * 32 + l];
    }
    __syncthreads();
    float acc[4] = {0.f, 0.f, 0.f, 0.f};
#pragma unroll
    for (int l = 0; l < 32; ++l) {
        float wv = w2[(size_t)(f * 32 + l) * 1024 + d];
#pragma unroll
        for (int rr = 0; rr < 4; ++rr) acc[rr] = fmaf(mps[rr][l], wv, acc[rr]);
    }
    float mf = maa_f[d];
#pragma unroll
    for (int rr = 0; rr < 4; ++rr) {
        int r = r0 + rr, t = r & 2047;
        size_t i = (size_t)r * 1024 + d;
        float xv = x[i];
        float xp = (t > 0) ? x[i - 1024] : 0.f;
        xs[i] = __float2bfloat16(xv + (xp - xv) * (mf + acc[rr]));
    }
}

// ---------------- fused pair of streams sharing x/mp loads ----------------
__global__ __launch_bounds__(256)
void mix_stream2(const float* __restrict__ mp, const float* __restrict__ w2,
                 const float* __restrict__ x,
                 const float* __restrict__ maa_a, const float* __restrict__ maa_b,
                 int fa, int fb, bf16* __restrict__ xsa, bf16* __restrict__ xsb)
{
    __shared__ float mpsa[4][32], mpsb[4][32];
    int dg = blockIdx.x, r0 = blockIdx.y * 4, tid = threadIdx.x;
    int d = dg * 256 + tid;
    if (tid < 128) {
        int rr = tid >> 5, l = tid & 31;
        mpsa[rr][l] = mp[(size_t)(r0 + rr) * 256 + fa * 32 + l];
        mpsb[rr][l] = mp[(size_t)(r0 + rr) * 256 + fb * 32 + l];
    }
    __syncthreads();
    float acca[4] = {0.f, 0.f, 0.f, 0.f}, accb[4] = {0.f, 0.f, 0.f, 0.f};
#pragma unroll
    for (int l = 0; l < 32; ++l) {
        float wa = w2[(size_t)(fa * 32 + l) * 1024 + d];
        float wbv = w2[(size_t)(fb * 32 + l) * 1024 + d];
#pragma unroll
        for (int rr = 0; rr < 4; ++rr) {
            acca[rr] = fmaf(mpsa[rr][l], wa, acca[rr]);
            accb[rr] = fmaf(mpsb[rr][l], wbv, accb[rr]);
        }
    }
    float ma = maa_a[d], mb = maa_b[d];
#pragma unroll
    for (int rr = 0; rr < 4; ++rr) {
        int r = r0 + rr, t = r & 2047;
        size_t i = (size_t)r * 1024 + d;
        float xv = x[i];
        float xp = (t > 0) ? x[i - 1024] : 0.f;
        float dx = xp - xv;
        xsa[i] = __float2bfloat16(xv + dx * (ma + acca[rr]));
        xsb[i] = __float2bfloat16(xv + dx * (mb + accb[rr]));
    }
}

// ================= chunked GLA scan via MFMA: NC=32, L=64, single-wave blocks =================
// Prep loops: NO dynamic-index rings (scratch hazard) — direct loads, unroll 8.

// Phase A: Sloc[v][k] = (Vt @ KiA) * aL[k], D[k] = aL[k].  KiA[t][k] = kb*exp(cum).
__global__ __launch_bounds__(64)
void chunk_state(const bf16* __restrict__ kG, const bf16* __restrict__ vG,
                 const bf16* __restrict__ wG,
                 float* __restrict__ Sloc, float* __restrict__ D)
{
    int c = blockIdx.x, bh = blockIdx.y;
    int b = bh >> 4, h = bh & 15;
    int lane = threadIdx.x;
    int row16 = lane & 15, quad = lane >> 4;
    __shared__ __align__(16) char smem[2 * 9216 + 256];
    bf16* sKiAt = (bf16*)smem;             // [k][t]
    bf16* sVt   = (bf16*)(smem + 9216);    // [v][t]
    float* aLs  = (float*)(smem + 18432);
    size_t base = (size_t)b * 2048 * 1024 + (size_t)h * 64 + (size_t)c * 64 * 1024;

    const unsigned short* kp = (const unsigned short*)kG;
    const unsigned short* vp = (const unsigned short*)vG;
    const unsigned short* wp = (const unsigned short*)wG;

    float A = 1.f;
#pragma unroll
    for (int t8 = 0; t8 < 64; t8 += 8) {
        unsigned short kk[8], vv8[8], ww[8];
#pragma unroll
        for (int j = 0; j < 8; ++j) {
            size_t a = base + (size_t)(t8 + j) * 1024 + lane;
            kk[j] = kp[a]; vv8[j] = vp[a]; ww[j] = wp[a];
        }
        union { unsigned short u[8]; uint4 q; } pk, pv;
#pragma unroll
        for (int j = 0; j < 8; ++j) {
            float el = __expf(-bf2f(ww[j]));
            A *= el;
            float kb = bf2f(kk[j]) * (1.f - el);
            pk.u[j] = f2bu(kb * RCPF(A));
            pv.u[j] = vv8[j];
        }
        *(uint4*)(sKiAt + lane * 72 + t8) = pk.q;
        *(uint4*)(sVt   + lane * 72 + t8) = pv.q;
    }
    aLs[lane] = A;
    D[((size_t)bh * 32 + c) * 64 + lane] = A;
    __syncthreads();

    f32x4 acc[4][4];
#pragma unroll
    for (int mi = 0; mi < 4; ++mi)
#pragma unroll
        for (int ni = 0; ni < 4; ++ni) acc[mi][ni] = (f32x4){0.f, 0.f, 0.f, 0.f};
#pragma unroll
    for (int kit = 0; kit < 2; ++kit) {
        bf16x8 af[4], bfr[4];
#pragma unroll
        for (int mi = 0; mi < 4; ++mi)
            af[mi] = *(const bf16x8*)(sVt + (mi * 16 + row16) * 72 + kit * 32 + quad * 8);
#pragma unroll
        for (int ni = 0; ni < 4; ++ni)
            bfr[ni] = *(const bf16x8*)(sKiAt + (ni * 16 + row16) * 72 + kit * 32 + quad * 8);
#pragma unroll
        for (int mi = 0; mi < 4; ++mi)
#pragma unroll
            for (int ni = 0; ni < 4; ++ni)
                acc[mi][ni] = __builtin_amdgcn_mfma_f32_16x16x32_bf16(af[mi], bfr[ni], acc[mi][ni], 0, 0, 0);
    }
    float* So = Sloc + ((size_t)bh * 32 + c) * 4096;
#pragma unroll
    for (int mi = 0; mi < 4; ++mi)
#pragma unroll
        for (int ni = 0; ni < 4; ++ni)
#pragma unroll
            for (int r = 0; r < 4; ++r) {
                int rv = mi * 16 + quad * 4 + r;   // v
                int ck = ni * 16 + row16;          // k
                So[(size_t)rv * 64 + ck] = acc[mi][ni][r] * aLs[ck];
            }
}

// Phase B: S0_{c+1} = S0_c*D_c + Sloc_c (exact f32); Sloc_c := S0_c.
__global__ __launch_bounds__(256)
void chunk_combine(float* __restrict__ Sloc, const float* __restrict__ D)
{
    int bh = blockIdx.x;
    int tid = threadIdx.x;
    int k = tid & 63, v0 = tid >> 6;
    float s[16];
#pragma unroll
    for (int j = 0; j < 16; ++j) s[j] = 0.f;
    for (int c = 0; c < 32; ++c) {
        float Dk = D[((size_t)bh * 32 + c) * 64 + k];
        size_t basei = ((size_t)bh * 32 + c) * 4096 + k;
#pragma unroll
        for (int j = 0; j < 16; ++j) {
            size_t idx = basei + (size_t)(v0 + j * 4) * 64;
            float tmp = Sloc[idx];
            Sloc[idx] = s[j];
            s[j] = s[j] * Dk + tmp;
        }
    }
}

// Phase C: P=(Q⊙A)(KB⊘A)^T masked; O = P@V + (Q⊙A)@S0; ag = O*gate (in-place).
__global__ __launch_bounds__(64)
void chunk_out(const bf16* __restrict__ qG, const bf16* __restrict__ kG,
               const bf16* __restrict__ vG, const bf16* __restrict__ wG,
               const bf16* gate, const float* __restrict__ S0buf, bf16* ag)
{
    int c = blockIdx.x, bh = blockIdx.y;
    int b = bh >> 4, h = bh & 15;
    int lane = threadIdx.x;
    int row16 = lane & 15, quad = lane >> 4;
    __shared__ __align__(16) char smem[4 * 9216];
    bf16*     sQA = (bf16*)smem;                  // [t][k] bf16
    bf16*     sKiA = (bf16*)(smem + 9216);        // [s][k] bf16; later P
    _Float16* sP  = (_Float16*)(smem + 9216);     // [t][s] f16 (overlays sKiA)
    _Float16* sVt = (_Float16*)(smem + 18432);    // [v][s] f16
    bf16*     sS0 = (bf16*)(smem + 27648);        // [v][k] bf16
    float*    Obuf = (float*)smem;                // [t][v] f32 (overlays sQA+sP after MFMA)
    size_t base = (size_t)b * 2048 * 1024 + (size_t)h * 64 + (size_t)c * 64 * 1024;

    // stage S0 (chunk-start state; buffer[v][k] = math S0[k][v] = Bt-form for QA@S0)
    const float* S0g = S0buf + ((size_t)bh * 32 + c) * 4096;
#pragma unroll 8
    for (int i = 0; i < 64; ++i)
        sS0[i * 72 + lane] = __float2bfloat16(S0g[(size_t)i * 64 + lane]);

    // prep: lane = k (and v for Vt). direct loads, unroll 8 (no rings)
    const unsigned short* qp = (const unsigned short*)qG;
    const unsigned short* kp = (const unsigned short*)kG;
    const unsigned short* vp = (const unsigned short*)vG;
    const unsigned short* wp = (const unsigned short*)wG;

    float A = 1.f;
#pragma unroll
    for (int t8 = 0; t8 < 64; t8 += 8) {
        unsigned short qq[8], kk[8], vv8[8], ww[8];
#pragma unroll
        for (int j = 0; j < 8; ++j) {
            size_t a = base + (size_t)(t8 + j) * 1024 + lane;
            qq[j] = qp[a]; kk[j] = kp[a]; vv8[j] = vp[a]; ww[j] = wp[a];
        }
        union { _Float16 hp[8]; uint4 q; } pv;
#pragma unroll
        for (int j = 0; j < 8; ++j) {
            int t = t8 + j;
            float el = __expf(-bf2f(ww[j]));
            A *= el;
            float kb = bf2f(kk[j]) * (1.f - el);
            sQA[t * 72 + lane]  = __float2bfloat16(bf2f(qq[j]) * 0.125f * A);
            sKiA[t * 72 + lane] = __float2bfloat16(kb * RCPF(A));
            pv.hp[j] = (_Float16)bf2f(vv8[j]);
        }
        *(uint4*)(sVt + lane * 72 + t8) = pv.q;
    }
    __syncthreads();

    // P = QA @ KiA^T  (contraction over k)
    f32x4 pacc[4][4];
#pragma unroll
    for (int mi = 0; mi < 4; ++mi)
#pragma unroll
        for (int ni = 0; ni < 4; ++ni) pacc[mi][ni] = (f32x4){0.f, 0.f, 0.f, 0.f};
#pragma unroll
    for (int kit = 0; kit < 2; ++kit) {
        bf16x8 af[4], bfr[4];
#pragma unroll
        for (int mi = 0; mi < 4; ++mi)
            af[mi] = *(const bf16x8*)(sQA + (mi * 16 + row16) * 72 + kit * 32 + quad * 8);
#pragma unroll
        for (int ni = 0; ni < 4; ++ni)
            bfr[ni] = *(const bf16x8*)(sKiA + (ni * 16 + row16) * 72 + kit * 32 + quad * 8);
#pragma unroll
        for (int mi = 0; mi < 4; ++mi)
#pragma unroll
            for (int ni = 0; ni < 4; ++ni)
                pacc[mi][ni] = __builtin_amdgcn_mfma_f32_16x16x32_bf16(af[mi], bfr[ni], pacc[mi][ni], 0, 0, 0);
    }
    __syncthreads();
    // mask (s<=t) and store P as f16 over sKiA
#pragma unroll
    for (int mi = 0; mi < 4; ++mi)
#pragma unroll
        for (int ni = 0; ni < 4; ++ni)
#pragma unroll
            for (int r = 0; r < 4; ++r) {
                int rowt = mi * 16 + quad * 4 + r;
                int cols = ni * 16 + row16;
                float pvv = (cols <= rowt) ? pacc[mi][ni][r] : 0.f;
                sP[rowt * 72 + cols] = (_Float16)pvv;
            }
    __syncthreads();

    // O = P @ V (f16) + QA @ S0 (bf16)
    f32x4 oacc[4][4];
#pragma unroll
    for (int mi = 0; mi < 4; ++mi)
#pragma unroll
        for (int ni = 0; ni < 4; ++ni) oacc[mi][ni] = (f32x4){0.f, 0.f, 0.f, 0.f};
#pragma unroll
    for (int kit = 0; kit < 2; ++kit) {
        f16x8 af[4], bfr[4];
#pragma unroll
        for (int mi = 0; mi < 4; ++mi)
            af[mi] = *(const f16x8*)(sP + (mi * 16 + row16) * 72 + kit * 32 + quad * 8);
#pragma unroll
        for (int ni = 0; ni < 4; ++ni)
            bfr[ni] = *(const f16x8*)(sVt + (ni * 16 + row16) * 72 + kit * 32 + quad * 8);
#pragma unroll
        for (int mi = 0; mi < 4; ++mi)
#pragma unroll
            for (int ni = 0; ni < 4; ++ni)
                oacc[mi][ni] = __builtin_amdgcn_mfma_f32_16x16x32_f16(af[mi], bfr[ni], oacc[mi][ni], 0, 0, 0);
    }
#pragma unroll
    for (int kit = 0; kit < 2; ++kit) {
        bf16x8 af[4], bfr[4];
#pragma unroll
        for (int mi = 0; mi < 4; ++mi)
            af[mi] = *(const bf16x8*)(sQA + (mi * 16 + row16) * 72 + kit * 32 + quad * 8);
#pragma unroll
        for (int ni = 0; ni < 4; ++ni)
            bfr[ni] = *(const bf16x8*)(sS0 + (ni * 16 + row16) * 72 + kit * 32 + quad * 8);
#pragma unroll
        for (int mi = 0; mi < 4; ++mi)
#pragma unroll
            for (int ni = 0; ni < 4; ++ni)
                oacc[mi][ni] = __builtin_amdgcn_mfma_f32_16x16x32_bf16(af[mi], bfr[ni], oacc[mi][ni], 0, 0, 0);
    }
    __syncthreads();
    // O -> LDS (f32, overlays sQA/sP — all MFMA reads complete)
#pragma unroll
    for (int mi = 0; mi < 4; ++mi)
#pragma unroll
        for (int ni = 0; ni < 4; ++ni)
#pragma unroll
            for (int r = 0; r < 4; ++r)
                Obuf[(mi * 16 + quad * 4 + r) * 72 + ni * 16 + row16] = oacc[mi][ni][r];
    __syncthreads();
    // epilogue: coalesced gate-multiply, in-place into ag(=gate buffer)
    const unsigned short* gp = (const unsigned short*)gate;
#pragma unroll 8
    for (int t = 0; t < 64; ++t) {
        size_t ad = base + (size_t)t * 1024 + lane;
        float o = Obuf[t * 72 + lane];
        float g = bf2f(gp[ad]);
        ag[ad] = __float2bfloat16(o * g);
    }
}

// ---------------- launch ----------------
extern "C" void kernel_launch(void* const* d_in, const int* in_sizes, int n_in,
                              void* d_out, int out_size, void* d_ws, size_t ws_size,
                              hipStream_t stream) {
    const float* x    = (const float*)d_in[0];
    const float* maax = (const float*)d_in[1];
    const float* maar = (const float*)d_in[2];
    const float* maak = (const float*)d_in[3];
    const float* maav = (const float*)d_in[4];
    const float* maaw = (const float*)d_in[5];
    const float* maag = (const float*)d_in[6];
    const float* w1   = (const float*)d_in[7];
    const float* w2   = (const float*)d_in[8];
    const float* td   = (const float*)d_in[9];
    const float* dw1  = (const float*)d_in[10];
    const float* dw2  = (const float*)d_in[11];
    const float* Wq   = (const float*)d_in[12];
    const float* Wk   = (const float*)d_in[13];
    const float* Wv   = (const float*)d_in[14];
    const float* Wo   = (const float*)d_in[15];
    const float* Wg   = (const float*)d_in[16];
    const float* bg   = (const float*)d_in[17];

    char* ws = (char*)d_ws;
    bf16*  xxx   = (bf16*) (ws + OFF_XXXQ);
    bf16*  qb    = (bf16*) (ws + OFF_XXXQ);
    bf16*  kb    = (bf16*) (ws + OFF_K);
    bf16*  vb    = (bf16*) (ws + OFF_V);
    bf16*  wb    = (bf16*) (ws + OFF_W);
    bf16*  gateb = (bf16*) (ws + OFF_GATE);
    bf16*  wqt   = (bf16*) (ws + OFF_WQT);
    bf16*  wkt   = (bf16*) (ws + OFF_WKT);
    float* mp    = (float*)(ws + OFF_MP);
    bf16*  xs0   = (bf16*) (ws + OFF_XS0);
    bf16*  xs1   = (bf16*) (ws + OFF_XS1);
    bf16*  wvt   = (bf16*) (ws + OFF_WVT);
    bf16*  wgt   = (bf16*) (ws + OFF_WGT);
    bf16*  wot   = (bf16*) (ws + OFF_WOT);
    bf16*  w1t   = (bf16*) (ws + OFF_W1T);
    bf16*  wd1t  = (bf16*) (ws + OFF_WD1T);
    bf16*  wd2t  = (bf16*) (ws + OFF_WD2T);
    bf16*  dect  = (bf16*) (ws + OFF_DECT);
    float* Sloc  = (float*)(ws + OFF_SLOC);   // overlays dead xs0/xs1
    float* Dbuf  = (float*)(ws + OFF_D);      // overlays dead w1t

    // fused transposes + prep_xxx
    transpose_all<<<5568 + 16384, dim3(32, 8), 0, stream>>>(
        Wq, Wk, Wv, Wg, Wo, w1, dw1, dw2,
        wqt, wkt, wvt, wgt, wot, w1t, wd1t, wd2t, x, maax, xxx);

    // mp = tanh(xxx @ W1)
    gemm_bt<1><<<dim3(32, 2), 256, 0, stream>>>(xxx, 1024, w1t, 1024, mp, 256, 1024, nullptr);

    // decay chain: xw -> dect -> wb = exp(decay)
    mix_stream<<<dim3(4, 1024), 256, 0, stream>>>(mp, w2, x, maaw, 3, xs0);
    gemm_bt<2><<<dim3(32, 1), 256, 0, stream>>>(xs0, 1024, wd1t, 1024, dect, 128, 1024, nullptr);
    gemm_bt<3><<<dim3(32, 8), 256, 0, stream>>>(dect, 128, wd2t, 64, wb, 1024, 64, td);

    // streams r,k -> q,k (batched)
    mix_stream2<<<dim3(4, 1024), 256, 0, stream>>>(mp, w2, x, maar, maak, 0, 1, xs0, xs1);
    gemm_bt2<5><<<dim3(32, 8, 2), 256, 0, stream>>>(xs0, xs1, 1024, wqt, wkt, 1024,
                                                    qb, kb, 1024, 1024, nullptr);

    // streams v,g -> v,gate (batched; gate overwrites dead wqt/wkt/mp)
    mix_stream2<<<dim3(4, 1024), 256, 0, stream>>>(mp, w2, x, maav, maag, 2, 4, xs0, xs1);
    gemm_bt2<4><<<dim3(32, 8, 2), 256, 0, stream>>>(xs0, xs1, 1024, wvt, wgt, 1024,
                                                    vb, gateb, 1024, 1024, bg);

    // chunked GLA scan via MFMA: NC=32, L=64
    chunk_state  <<<dim3(32, 32),  64, 0, stream>>>(kb, vb, wb, Sloc, Dbuf);
    chunk_combine<<<32,           256, 0, stream>>>(Sloc, Dbuf);
    chunk_out    <<<dim3(32, 32),  64, 0, stream>>>(qb, kb, vb, wb, gateb, Sloc, gateb);

    // out = (o*gate) @ Wo -> f32
    gemm_bt<6><<<dim3(32, 8), 256, 0, stream>>>(gateb, 1024, wot, 1024, (float*)d_out, 1024, 1024, nullptr);

    (void)in_sizes; (void)n_in; (void)out_size; (void)ws_size;
}